// Round 1
// baseline (1243.313 us; speedup 1.0000x reference)
//
#include <hip/hip_runtime.h>
#include <math.h>

#define BB 4
#define SS 2048
#define HH 8
#define DD 64
#define EPSV 1e-5f

// ---------------------------------------------------------------------------
// K1: fused LayerNorm1 + QKV projection.
// One wave (64 lanes) per (b,s,h) row. lane = d index.
// Writes Q,K,V transposed to [B,H,S,D] so attention reads are row-contiguous.
// ---------------------------------------------------------------------------
__global__ __launch_bounds__(256) void k1_ln_qkv(
    const float* __restrict__ x, const float* __restrict__ g1, const float* __restrict__ b1v,
    const float* __restrict__ Wp, const float* __restrict__ bp,
    float* __restrict__ qws, float* __restrict__ kws, float* __restrict__ vws)
{
    const int wave = threadIdx.x >> 6;
    const int lane = threadIdx.x & 63;
    const int row  = blockIdx.x * 4 + wave;          // (b*S + s)*H + h
    const int h = row % HH;
    const int s = (row / HH) % SS;
    const int b = row / (HH * SS);

    float xv = x[(size_t)row * 64 + lane];
    float m = xv;
    #pragma unroll
    for (int off = 32; off > 0; off >>= 1) m += __shfl_xor(m, off, 64);
    m *= (1.0f / 64.0f);
    float dx = xv - m;
    float var = dx * dx;
    #pragma unroll
    for (int off = 32; off > 0; off >>= 1) var += __shfl_xor(var, off, 64);
    var *= (1.0f / 64.0f);
    float hval = dx * rsqrtf(var + EPSV) * g1[lane] + b1v[lane];

    float a0 = bp[lane], a1 = bp[64 + lane], a2 = bp[128 + lane];
    #pragma unroll 16
    for (int i = 0; i < 64; ++i) {
        float hi = __shfl(hval, i, 64);
        const float* wrow = Wp + i * 192;
        a0 += hi * wrow[lane];
        a1 += hi * wrow[64 + lane];
        a2 += hi * wrow[128 + lane];
    }
    const int bh = b * HH + h;
    const size_t dst = ((size_t)bh * SS + s) * 64 + lane;
    qws[dst] = a0;
    kws[dst] = a1;
    vws[dst] = a2;
}

// ---------------------------------------------------------------------------
// K2: flash-style attention, fp32 (VALU), no scaling, no mask.
// Block: 256 threads; Q tile = 64 queries, K tile = 32 keys.
// Thread (tq=tid>>4, tk=tid&15): owns q rows {tq+16i}, k cols {tk+16j},
// output dims {4*tk+c}. 16-lane groups share a q row (shuffle reductions).
// LDS strides padded for b128 alignment + <=2-way bank conflicts (free).
// ---------------------------------------------------------------------------
#define QT 64
#define KT 32
#define QSTR 68   // 272B rows: 16B aligned, bank stride 4 -> 2-way max
#define KSTR 68
#define VSTR 68
#define PSTR 36   // 144B rows: 16B aligned

__global__ __launch_bounds__(256) void k2_attn(
    const float* __restrict__ qws, const float* __restrict__ kws,
    const float* __restrict__ vws, float* __restrict__ ows)
{
    __shared__ float Qs[QT * QSTR];
    __shared__ float Ks[KT * KSTR];
    __shared__ float Vs[KT * VSTR];
    __shared__ float Ps[QT * PSTR];

    const int tid = threadIdx.x;
    const int bh  = blockIdx.y;
    const int q0  = blockIdx.x * QT;
    const float* qb = qws + ((size_t)bh * SS + q0) * 64;
    const float* kb = kws + (size_t)bh * SS * 64;
    const float* vb = vws + (size_t)bh * SS * 64;

    // stage Q tile (64x64): 1024 float4 / 256 threads = 4 each, coalesced
    #pragma unroll
    for (int p = 0; p < 4; ++p) {
        int idx = tid + p * 256;
        int r = idx >> 4, c4 = idx & 15;
        *(float4*)(&Qs[r * QSTR + c4 * 4]) = *(const float4*)(qb + r * 64 + c4 * 4);
    }

    const int tq = tid >> 4;   // 0..15
    const int tk = tid & 15;   // 0..15

    float mrow[4], lrow[4], oacc[4][4];
    #pragma unroll
    for (int i = 0; i < 4; ++i) {
        mrow[i] = -1e30f; lrow[i] = 0.0f;
        #pragma unroll
        for (int c = 0; c < 4; ++c) oacc[i][c] = 0.0f;
    }

    __syncthreads();

    for (int kt = 0; kt < SS / KT; ++kt) {
        const float* kp = kb + (size_t)kt * KT * 64;
        const float* vp = vb + (size_t)kt * KT * 64;
        #pragma unroll
        for (int p = 0; p < 2; ++p) {
            int idx = tid + p * 256;           // 0..511
            int r = idx >> 4, c4 = idx & 15;
            *(float4*)(&Ks[r * KSTR + c4 * 4]) = *(const float4*)(kp + r * 64 + c4 * 4);
            *(float4*)(&Vs[r * VSTR + c4 * 4]) = *(const float4*)(vp + r * 64 + c4 * 4);
        }
        __syncthreads();

        // GEMM1: sacc[i][j] = sum_d Q[tq+16i][d] * K[tk+16j][d]
        float sacc[4][2];
        #pragma unroll
        for (int i = 0; i < 4; ++i) { sacc[i][0] = 0.0f; sacc[i][1] = 0.0f; }
        #pragma unroll
        for (int d4 = 0; d4 < 16; ++d4) {
            float4 qv[4], kv[2];
            #pragma unroll
            for (int i = 0; i < 4; ++i) qv[i] = *(const float4*)(&Qs[(tq + 16*i) * QSTR + d4*4]);
            #pragma unroll
            for (int j = 0; j < 2; ++j) kv[j] = *(const float4*)(&Ks[(tk + 16*j) * KSTR + d4*4]);
            #pragma unroll
            for (int i = 0; i < 4; ++i)
                #pragma unroll
                for (int j = 0; j < 2; ++j)
                    sacc[i][j] += qv[i].x*kv[j].x + qv[i].y*kv[j].y
                                + qv[i].z*kv[j].z + qv[i].w*kv[j].w;
        }

        // online softmax per q row; 16-lane group shares row (xor 1,2,4,8)
        #pragma unroll
        for (int i = 0; i < 4; ++i) {
            float tmax = fmaxf(sacc[i][0], sacc[i][1]);
            #pragma unroll
            for (int off = 1; off < 16; off <<= 1) tmax = fmaxf(tmax, __shfl_xor(tmax, off, 64));
            float newm  = fmaxf(mrow[i], tmax);
            float alpha = __expf(mrow[i] - newm);
            float p0 = __expf(sacc[i][0] - newm);
            float p1 = __expf(sacc[i][1] - newm);
            float ps = p0 + p1;
            #pragma unroll
            for (int off = 1; off < 16; off <<= 1) ps += __shfl_xor(ps, off, 64);
            lrow[i] = lrow[i] * alpha + ps;
            mrow[i] = newm;
            #pragma unroll
            for (int c = 0; c < 4; ++c) oacc[i][c] *= alpha;
            Ps[(tq + 16*i) * PSTR + tk]      = p0;
            Ps[(tq + 16*i) * PSTR + tk + 16] = p1;
        }
        __syncthreads();

        // GEMM2: oacc[i][c] += sum_k Ps[q][k] * Vs[k][4tk+c]
        #pragma unroll
        for (int k4 = 0; k4 < KT / 4; ++k4) {
            float4 pv[4], vv[4];
            #pragma unroll
            for (int i = 0; i < 4; ++i)  pv[i] = *(const float4*)(&Ps[(tq + 16*i) * PSTR + k4*4]);
            #pragma unroll
            for (int kk = 0; kk < 4; ++kk) vv[kk] = *(const float4*)(&Vs[(k4*4 + kk) * VSTR + 4*tk]);
            #pragma unroll
            for (int i = 0; i < 4; ++i) {
                oacc[i][0] += pv[i].x*vv[0].x + pv[i].y*vv[1].x + pv[i].z*vv[2].x + pv[i].w*vv[3].x;
                oacc[i][1] += pv[i].x*vv[0].y + pv[i].y*vv[1].y + pv[i].z*vv[2].y + pv[i].w*vv[3].y;
                oacc[i][2] += pv[i].x*vv[0].z + pv[i].y*vv[1].z + pv[i].z*vv[2].z + pv[i].w*vv[3].z;
                oacc[i][3] += pv[i].x*vv[0].w + pv[i].y*vv[1].w + pv[i].z*vv[2].w + pv[i].w*vv[3].w;
            }
        }
        __syncthreads();
    }

    #pragma unroll
    for (int i = 0; i < 4; ++i) {
        float inv = 1.0f / lrow[i];
        float4 ov = make_float4(oacc[i][0]*inv, oacc[i][1]*inv, oacc[i][2]*inv, oacc[i][3]*inv);
        *(float4*)(ows + ((size_t)bh * SS + q0 + tq + 16*i) * 64 + 4*tk) = ov;
    }
}

// ---------------------------------------------------------------------------
// K3: LayerNorm2 + MLP (exact-erf GELU) + residual.
// One wave per row; rows indexed [B,H,S] (attention-out layout), residual x
// read from [B,S,H] layout; output written in [B,S,H,D].
// ---------------------------------------------------------------------------
__global__ __launch_bounds__(256) void k3_ln_mlp(
    const float* __restrict__ ows, const float* __restrict__ x,
    const float* __restrict__ g2, const float* __restrict__ b2v,
    const float* __restrict__ W1, const float* __restrict__ b1,
    const float* __restrict__ W2, const float* __restrict__ b2o,
    float* __restrict__ out)
{
    const int wave = threadIdx.x >> 6;
    const int lane = threadIdx.x & 63;
    const int r = blockIdx.x * 4 + wave;          // (b*H + h)*S + s
    const int s = r % SS;
    const int h = (r / SS) % HH;
    const int b = r / (SS * HH);
    const size_t xrow = ((size_t)(b * SS + s) * HH + h);

    float ov = ows[(size_t)r * 64 + lane];
    float m = ov;
    #pragma unroll
    for (int off = 32; off > 0; off >>= 1) m += __shfl_xor(m, off, 64);
    m *= (1.0f / 64.0f);
    float dv = ov - m;
    float var = dv * dv;
    #pragma unroll
    for (int off = 32; off > 0; off >>= 1) var += __shfl_xor(var, off, 64);
    var *= (1.0f / 64.0f);
    float h2 = dv * rsqrtf(var + EPSV) * g2[lane] + b2v[lane];

    float outacc = b2o[lane] + x[xrow * 64 + lane];
    #pragma unroll
    for (int jc = 0; jc < 4; ++jc) {
        const int j = jc * 64 + lane;
        float acc = b1[j];
        #pragma unroll 16
        for (int i2 = 0; i2 < 64; ++i2)
            acc += __shfl(h2, i2, 64) * W1[i2 * 256 + j];
        float gj = 0.5f * acc * (1.0f + erff(acc * 0.70710678118654752f));
        #pragma unroll 16
        for (int i2 = 0; i2 < 64; ++i2)
            outacc += __shfl(gj, i2, 64) * W2[(jc * 64 + i2) * 64 + lane];
    }
    out[xrow * 64 + lane] = outacc;
}

// ---------------------------------------------------------------------------
extern "C" void kernel_launch(void* const* d_in, const int* in_sizes, int n_in,
                              void* d_out, int out_size, void* d_ws, size_t ws_size,
                              hipStream_t stream) {
    const float* x     = (const float*)d_in[0];
    const float* ln1_g = (const float*)d_in[1];
    const float* ln1_b = (const float*)d_in[2];
    const float* Wp    = (const float*)d_in[3];
    const float* bp    = (const float*)d_in[4];
    const float* ln2_g = (const float*)d_in[5];
    const float* ln2_b = (const float*)d_in[6];
    const float* W1    = (const float*)d_in[7];
    const float* b1    = (const float*)d_in[8];
    const float* W2    = (const float*)d_in[9];
    const float* b2    = (const float*)d_in[10];
    float* out = (float*)d_out;

    // workspace layout (floats): Q | K | V | O, each B*H*S*D = 4,194,304
    float* ws  = (float*)d_ws;
    float* qws = ws;
    float* kws = ws + 4194304;
    float* vws = ws + 8388608;
    float* ows = ws + 12582912;   // total 67.1 MB required

    k1_ln_qkv<<<dim3(BB * SS * HH / 4), dim3(256), 0, stream>>>(
        x, ln1_g, ln1_b, Wp, bp, qws, kws, vws);
    k2_attn<<<dim3(SS / QT, BB * HH), dim3(256), 0, stream>>>(qws, kws, vws, ows);
    k3_ln_mlp<<<dim3(BB * HH * SS / 4), dim3(256), 0, stream>>>(
        ows, x, ln2_g, ln2_b, W1, b1, W2, b2, out);
}

// Round 2
// 589.873 us; speedup vs baseline: 2.1078x; 2.1078x over previous
//
#include <hip/hip_runtime.h>
#include <math.h>

#define BB 4
#define SS 2048
#define HH 8
#define DD 64
#define EPSV 1e-5f

typedef __attribute__((ext_vector_type(8))) short short8;
typedef __attribute__((ext_vector_type(4))) float f32x4;
#define MFMA16 __builtin_amdgcn_mfma_f32_16x16x32_bf16

__device__ inline unsigned short f2bf(float f) {
    unsigned u = __builtin_bit_cast(unsigned, f);
    unsigned r = (u + 0x7fffu + ((u >> 16) & 1u)) >> 16;
    return (unsigned short)r;
}
__device__ inline float bf2f(unsigned short h) {
    unsigned u = ((unsigned)h) << 16;
    return __builtin_bit_cast(float, u);
}

// ---------------------------------------------------------------------------
// K1: LN1 + QKV projection. 4 rows per wave (W loads amortized 4x).
// Q written fp32 [B,H,S,D]; K written as bf16 hi+lo pair; V as bf16.
// ---------------------------------------------------------------------------
__global__ __launch_bounds__(256) void k1_ln_qkv(
    const float* __restrict__ x, const float* __restrict__ g1, const float* __restrict__ b1v,
    const float* __restrict__ Wp, const float* __restrict__ bp,
    float* __restrict__ qws, unsigned short* __restrict__ khws,
    unsigned short* __restrict__ klws, unsigned short* __restrict__ vbf)
{
    const int wave = threadIdx.x >> 6;
    const int lane = threadIdx.x & 63;
    const int r0 = (blockIdx.x * 4 + wave) * 4;      // 4 rows, (b*S+s)*H+h order

    float hv[4];
    #pragma unroll
    for (int j = 0; j < 4; ++j) {
        float xv = x[(size_t)(r0 + j) * 64 + lane];
        float m = xv;
        #pragma unroll
        for (int off = 32; off > 0; off >>= 1) m += __shfl_xor(m, off, 64);
        m *= (1.0f / 64.0f);
        float dx = xv - m;
        float var = dx * dx;
        #pragma unroll
        for (int off = 32; off > 0; off >>= 1) var += __shfl_xor(var, off, 64);
        var *= (1.0f / 64.0f);
        hv[j] = dx * rsqrtf(var + EPSV) * g1[lane] + b1v[lane];
    }

    float a0[4], a1[4], a2[4];
    #pragma unroll
    for (int j = 0; j < 4; ++j) { a0[j] = bp[lane]; a1[j] = bp[64 + lane]; a2[j] = bp[128 + lane]; }

    #pragma unroll 8
    for (int i = 0; i < 64; ++i) {
        float w0 = Wp[i * 192 + lane];
        float w1 = Wp[i * 192 + 64 + lane];
        float w2 = Wp[i * 192 + 128 + lane];
        #pragma unroll
        for (int j = 0; j < 4; ++j) {
            float h = __shfl(hv[j], i, 64);
            a0[j] += h * w0; a1[j] += h * w1; a2[j] += h * w2;
        }
    }

    #pragma unroll
    for (int j = 0; j < 4; ++j) {
        int row = r0 + j;
        int h = row & 7, s = (row >> 3) & 2047, b = row >> 14;
        size_t dst = ((size_t)(b * 8 + h) * 2048 + s) * 64 + lane;
        qws[dst] = a0[j];
        unsigned short kh = f2bf(a1[j]);
        khws[dst] = kh;
        klws[dst] = f2bf(a1[j] - bf2f(kh));
        vbf[dst] = f2bf(a2[j]);
    }
}

// ---------------------------------------------------------------------------
// K2: flash attention with bf16 MFMA (16x16x32), split-precision QK^T.
// 4 waves/block, 16 queries/wave (Q tile 64), K tile 64.
// S^T = K·Q^T  (A = K tile from LDS, B = Q frags in registers).
// Softmax state per lane keyed by q = lane&15; P LDS round-trip to A-layout.
// ---------------------------------------------------------------------------
#define KT2 64
#define LROW 72   // LDS row stride in bf16 elements (144 B: 16B-aligned + pad)

__global__ __launch_bounds__(256) void k2_attn(
    const float* __restrict__ qws, const unsigned short* __restrict__ khws,
    const unsigned short* __restrict__ klws, const unsigned short* __restrict__ vbf,
    float* __restrict__ ows)
{
    __shared__ __align__(16) unsigned short KhL[64 * LROW];
    __shared__ __align__(16) unsigned short KlL[64 * LROW];
    __shared__ __align__(16) unsigned short VtL[64 * LROW];   // [dim][key]
    __shared__ __align__(16) unsigned short PL[4 * 16 * LROW];

    const int tid  = threadIdx.x;
    const int w    = tid >> 6;
    const int lane = tid & 63;
    const int l15  = lane & 15;
    const int g    = lane >> 4;            // 0..3
    const int bh   = blockIdx.y;
    const int qb0  = blockIdx.x * 64;

    // ---- Q B-frags (fixed): n = q = l15, k = dim = 32*kh + 8*g + j ----
    short8 qh[2], ql[2];
    {
        const float* qp = qws + ((size_t)bh * SS + qb0 + w * 16 + l15) * 64;
        #pragma unroll
        for (int kh = 0; kh < 2; ++kh) {
            const float* p = qp + 32 * kh + 8 * g;
            #pragma unroll
            for (int j = 0; j < 8; ++j) {
                float f = p[j];
                unsigned short hi = f2bf(f);
                qh[kh][j] = (short)hi;
                ql[kh][j] = (short)f2bf(f - bf2f(hi));
            }
        }
    }

    float mrow = -1e30f, lrow = 0.0f;
    f32x4 oacc[4];
    #pragma unroll
    for (int dt = 0; dt < 4; ++dt) oacc[dt] = (f32x4){0.f, 0.f, 0.f, 0.f};

    const size_t kvbase = (size_t)bh * SS * 64;

    for (int kt = 0; kt < SS / KT2; ++kt) {
        // ---- stage K hi/lo (copy) and V (transpose) into LDS ----
        {
            #pragma unroll
            for (int rr = 0; rr < 2; ++rr) {
                int slot = tid + 256 * rr;          // 0..511
                int key = slot >> 3, seg = slot & 7;
                size_t src = kvbase + (size_t)(kt * KT2 + key) * 64 + seg * 8;
                *(uint4*)(&KhL[key * LROW + seg * 8]) = *(const uint4*)(khws + src);
                *(uint4*)(&KlL[key * LROW + seg * 8]) = *(const uint4*)(klws + src);
            }
            int d2 = tid & 31;                       // dim pair
            int kg = tid >> 5;                       // 0..7 key group
            const unsigned short* vp = vbf + kvbase + (size_t)(kt * KT2 + kg * 8) * 64 + d2 * 2;
            unsigned wv[8];
            #pragma unroll
            for (int j = 0; j < 8; ++j) wv[j] = *(const unsigned*)(vp + j * 64);
            uint4 E, O;
            E.x = (wv[0] & 0xffffu) | (wv[1] << 16);
            E.y = (wv[2] & 0xffffu) | (wv[3] << 16);
            E.z = (wv[4] & 0xffffu) | (wv[5] << 16);
            E.w = (wv[6] & 0xffffu) | (wv[7] << 16);
            O.x = (wv[0] >> 16) | (wv[1] & 0xffff0000u);
            O.y = (wv[2] >> 16) | (wv[3] & 0xffff0000u);
            O.z = (wv[4] >> 16) | (wv[5] & 0xffff0000u);
            O.w = (wv[6] >> 16) | (wv[7] & 0xffff0000u);
            *(uint4*)(&VtL[(2 * d2) * LROW + kg * 8]) = E;
            *(uint4*)(&VtL[(2 * d2 + 1) * LROW + kg * 8]) = O;
        }
        __syncthreads();

        // ---- S^T = K·Q^T : 4 key-subtiles of 16, split-precision ----
        f32x4 st[4];
        #pragma unroll
        for (int nf = 0; nf < 4; ++nf) {
            f32x4 acc = (f32x4){0.f, 0.f, 0.f, 0.f};
            #pragma unroll
            for (int kh = 0; kh < 2; ++kh) {
                int off = (nf * 16 + l15) * LROW + 32 * kh + 8 * g;
                short8 kah = *(const short8*)(&KhL[off]);
                short8 kal = *(const short8*)(&KlL[off]);
                acc = MFMA16(kah, qh[kh], acc, 0, 0, 0);
                acc = MFMA16(kah, ql[kh], acc, 0, 0, 0);
                acc = MFMA16(kal, qh[kh], acc, 0, 0, 0);
            }
            st[nf] = acc;   // element: key = kt*64 + nf*16 + 4g + r ; q = qb0+w*16+l15
        }

        // ---- online softmax (state keyed by q = l15) ----
        float tmax = -1e30f;
        #pragma unroll
        for (int nf = 0; nf < 4; ++nf)
            #pragma unroll
            for (int r = 0; r < 4; ++r) tmax = fmaxf(tmax, st[nf][r]);
        tmax = fmaxf(tmax, __shfl_xor(tmax, 16, 64));
        tmax = fmaxf(tmax, __shfl_xor(tmax, 32, 64));
        float newm = fmaxf(mrow, tmax);
        float alpha = __expf(mrow - newm);
        mrow = newm;
        float psum = 0.0f;
        #pragma unroll
        for (int nf = 0; nf < 4; ++nf) {
            unsigned short pb[4];
            #pragma unroll
            for (int r = 0; r < 4; ++r) {
                float p = __expf(st[nf][r] - newm);
                psum += p;
                pb[r] = f2bf(p);
            }
            uint2 pk;
            pk.x = (unsigned)pb[0] | ((unsigned)pb[1] << 16);
            pk.y = (unsigned)pb[2] | ((unsigned)pb[3] << 16);
            *(uint2*)(&PL[(w * 16 + l15) * LROW + nf * 16 + 4 * g]) = pk;
        }
        psum += __shfl_xor(psum, 16, 64);
        psum += __shfl_xor(psum, 32, 64);
        lrow = lrow * alpha + psum;

        // rescale O by alpha of row q = 4g + reg
        #pragma unroll
        for (int r = 0; r < 4; ++r) {
            float ar = __shfl(alpha, 4 * g + r, 64);
            #pragma unroll
            for (int dt = 0; dt < 4; ++dt) oacc[dt][r] *= ar;
        }

        // ---- O += P·V ----
        #pragma unroll
        for (int k2 = 0; k2 < 2; ++k2) {
            short8 pa = *(const short8*)(&PL[(w * 16 + l15) * LROW + k2 * 32 + 8 * g]);
            #pragma unroll
            for (int dt = 0; dt < 4; ++dt) {
                short8 vb = *(const short8*)(&VtL[(16 * dt + l15) * LROW + k2 * 32 + 8 * g]);
                oacc[dt] = MFMA16(pa, vb, oacc[dt], 0, 0, 0);
            }
        }
        __syncthreads();
    }

    // ---- epilogue: normalize and store fp32 ----
    float il = 1.0f / lrow;
    #pragma unroll
    for (int r = 0; r < 4; ++r) {
        float ilr = __shfl(il, 4 * g + r, 64);
        int row = qb0 + w * 16 + 4 * g + r;
        #pragma unroll
        for (int dt = 0; dt < 4; ++dt)
            ows[((size_t)bh * SS + row) * 64 + dt * 16 + l15] = oacc[dt][r] * ilr;
    }
}

// ---------------------------------------------------------------------------
// K3: LN2 + MLP (exact erf GELU) + residual. 4 rows per wave.
// ---------------------------------------------------------------------------
__global__ __launch_bounds__(256) void k3_ln_mlp(
    const float* __restrict__ ows, const float* __restrict__ x,
    const float* __restrict__ g2, const float* __restrict__ b2v,
    const float* __restrict__ W1, const float* __restrict__ b1m,
    const float* __restrict__ W2, const float* __restrict__ b2o,
    float* __restrict__ out)
{
    const int wave = threadIdx.x >> 6;
    const int lane = threadIdx.x & 63;
    const int r0 = (blockIdx.x * 4 + wave) * 4;      // (b*H+h)*S + s order

    float h2[4];
    float outacc[4];
    #pragma unroll
    for (int j = 0; j < 4; ++j) {
        int r = r0 + j;
        float ov = ows[(size_t)r * 64 + lane];
        float m = ov;
        #pragma unroll
        for (int off = 32; off > 0; off >>= 1) m += __shfl_xor(m, off, 64);
        m *= (1.0f / 64.0f);
        float dv = ov - m;
        float var = dv * dv;
        #pragma unroll
        for (int off = 32; off > 0; off >>= 1) var += __shfl_xor(var, off, 64);
        var *= (1.0f / 64.0f);
        h2[j] = dv * rsqrtf(var + EPSV) * g2[lane] + b2v[lane];

        int s = r & 2047, h = (r >> 11) & 7, b = r >> 14;
        outacc[j] = b2o[lane] + x[((size_t)(b * SS + s) * HH + h) * 64 + lane];
    }

    #pragma unroll
    for (int jc = 0; jc < 4; ++jc) {
        const int jj = jc * 64 + lane;
        float acc[4];
        #pragma unroll
        for (int j = 0; j < 4; ++j) acc[j] = b1m[jj];
        #pragma unroll 8
        for (int i = 0; i < 64; ++i) {
            float wv = W1[i * 256 + jj];
            #pragma unroll
            for (int j = 0; j < 4; ++j) acc[j] += __shfl(h2[j], i, 64) * wv;
        }
        float gj[4];
        #pragma unroll
        for (int j = 0; j < 4; ++j)
            gj[j] = 0.5f * acc[j] * (1.0f + erff(acc[j] * 0.70710678118654752f));
        #pragma unroll 8
        for (int i = 0; i < 64; ++i) {
            float wv = W2[(jc * 64 + i) * 64 + lane];
            #pragma unroll
            for (int j = 0; j < 4; ++j) outacc[j] += __shfl(gj[j], i, 64) * wv;
        }
    }

    #pragma unroll
    for (int j = 0; j < 4; ++j) {
        int r = r0 + j;
        int s = r & 2047, h = (r >> 11) & 7, b = r >> 14;
        out[((size_t)(b * SS + s) * HH + h) * 64 + lane] = outacc[j];
    }
}

// ---------------------------------------------------------------------------
extern "C" void kernel_launch(void* const* d_in, const int* in_sizes, int n_in,
                              void* d_out, int out_size, void* d_ws, size_t ws_size,
                              hipStream_t stream) {
    const float* x     = (const float*)d_in[0];
    const float* ln1_g = (const float*)d_in[1];
    const float* ln1_b = (const float*)d_in[2];
    const float* Wp    = (const float*)d_in[3];
    const float* bp    = (const float*)d_in[4];
    const float* ln2_g = (const float*)d_in[5];
    const float* ln2_b = (const float*)d_in[6];
    const float* W1    = (const float*)d_in[7];
    const float* b1    = (const float*)d_in[8];
    const float* W2    = (const float*)d_in[9];
    const float* b2    = (const float*)d_in[10];
    float* out = (float*)d_out;

    // workspace: qws f32 | ows f32 | khws bf16 | klws bf16 | vbf bf16  (58.7 MB)
    float* ws  = (float*)d_ws;
    float* qws = ws;
    float* ows = ws + 4194304;
    unsigned short* khws = (unsigned short*)(ws + 8388608);
    unsigned short* klws = khws + 4194304;
    unsigned short* vbf  = klws + 4194304;

    k1_ln_qkv<<<dim3(4096), dim3(256), 0, stream>>>(
        x, ln1_g, ln1_b, Wp, bp, qws, khws, klws, vbf);
    k2_attn<<<dim3(SS / 64, BB * HH), dim3(256), 0, stream>>>(
        qws, khws, klws, vbf, ows);
    k3_ln_mlp<<<dim3(4096), dim3(256), 0, stream>>>(
        ows, x, ln2_g, ln2_b, W1, b1, W2, b2, out);
}

// Round 3
// 284.012 us; speedup vs baseline: 4.3777x; 2.0769x over previous
//
#include <hip/hip_runtime.h>
#include <math.h>

#define BB 4
#define SS 2048
#define HH 8
#define DD 64
#define EPSV 1e-5f

typedef __attribute__((ext_vector_type(8))) short short8;
typedef __attribute__((ext_vector_type(4))) float f32x4;
#define MFMA16 __builtin_amdgcn_mfma_f32_16x16x32_bf16

__device__ inline unsigned short f2bf(float f) {
    unsigned u = __builtin_bit_cast(unsigned, f);
    unsigned r = (u + 0x7fffu + ((u >> 16) & 1u)) >> 16;
    return (unsigned short)r;
}
__device__ inline float bf2f(unsigned short h) {
    unsigned u = ((unsigned)h) << 16;
    return __builtin_bit_cast(float, u);
}

// ---------------------------------------------------------------------------
// K1: LN1 + QKV projection. 4 rows per wave (W loads amortized 4x).
// Q written fp32 [B,H,S,D]; K written as bf16 hi+lo pair; V as bf16.
// ---------------------------------------------------------------------------
__global__ __launch_bounds__(256) void k1_ln_qkv(
    const float* __restrict__ x, const float* __restrict__ g1, const float* __restrict__ b1v,
    const float* __restrict__ Wp, const float* __restrict__ bp,
    float* __restrict__ qws, unsigned short* __restrict__ khws,
    unsigned short* __restrict__ klws, unsigned short* __restrict__ vbf)
{
    const int wave = threadIdx.x >> 6;
    const int lane = threadIdx.x & 63;
    const int r0 = (blockIdx.x * 4 + wave) * 4;      // 4 rows, (b*S+s)*H+h order

    float hv[4];
    #pragma unroll
    for (int j = 0; j < 4; ++j) {
        float xv = x[(size_t)(r0 + j) * 64 + lane];
        float m = xv;
        #pragma unroll
        for (int off = 32; off > 0; off >>= 1) m += __shfl_xor(m, off, 64);
        m *= (1.0f / 64.0f);
        float dx = xv - m;
        float var = dx * dx;
        #pragma unroll
        for (int off = 32; off > 0; off >>= 1) var += __shfl_xor(var, off, 64);
        var *= (1.0f / 64.0f);
        hv[j] = dx * rsqrtf(var + EPSV) * g1[lane] + b1v[lane];
    }

    float a0[4], a1[4], a2[4];
    #pragma unroll
    for (int j = 0; j < 4; ++j) { a0[j] = bp[lane]; a1[j] = bp[64 + lane]; a2[j] = bp[128 + lane]; }

    #pragma unroll 8
    for (int i = 0; i < 64; ++i) {
        float w0 = Wp[i * 192 + lane];
        float w1 = Wp[i * 192 + 64 + lane];
        float w2 = Wp[i * 192 + 128 + lane];
        #pragma unroll
        for (int j = 0; j < 4; ++j) {
            float h = __shfl(hv[j], i, 64);
            a0[j] += h * w0; a1[j] += h * w1; a2[j] += h * w2;
        }
    }

    #pragma unroll
    for (int j = 0; j < 4; ++j) {
        int row = r0 + j;
        int h = row & 7, s = (row >> 3) & 2047, b = row >> 14;
        size_t dst = ((size_t)(b * 8 + h) * 2048 + s) * 64 + lane;
        qws[dst] = a0[j];
        unsigned short kh = f2bf(a1[j]);
        khws[dst] = kh;
        klws[dst] = f2bf(a1[j] - bf2f(kh));
        vbf[dst] = f2bf(a2[j]);
    }
}

// ---------------------------------------------------------------------------
// K2: flash attention with bf16 MFMA (16x16x32), split-precision QK^T.
// ---------------------------------------------------------------------------
#define KT2 64
#define LROW 72

__global__ __launch_bounds__(256) void k2_attn(
    const float* __restrict__ qws, const unsigned short* __restrict__ khws,
    const unsigned short* __restrict__ klws, const unsigned short* __restrict__ vbf,
    float* __restrict__ ows)
{
    __shared__ __align__(16) unsigned short KhL[64 * LROW];
    __shared__ __align__(16) unsigned short KlL[64 * LROW];
    __shared__ __align__(16) unsigned short VtL[64 * LROW];   // [dim][key]
    __shared__ __align__(16) unsigned short PL[4 * 16 * LROW];

    const int tid  = threadIdx.x;
    const int w    = tid >> 6;
    const int lane = tid & 63;
    const int l15  = lane & 15;
    const int g    = lane >> 4;
    const int bh   = blockIdx.y;
    const int qb0  = blockIdx.x * 64;

    short8 qh[2], ql[2];
    {
        const float* qp = qws + ((size_t)bh * SS + qb0 + w * 16 + l15) * 64;
        #pragma unroll
        for (int kh = 0; kh < 2; ++kh) {
            const float* p = qp + 32 * kh + 8 * g;
            #pragma unroll
            for (int j = 0; j < 8; ++j) {
                float f = p[j];
                unsigned short hi = f2bf(f);
                qh[kh][j] = (short)hi;
                ql[kh][j] = (short)f2bf(f - bf2f(hi));
            }
        }
    }

    float mrow = -1e30f, lrow = 0.0f;
    f32x4 oacc[4];
    #pragma unroll
    for (int dt = 0; dt < 4; ++dt) oacc[dt] = (f32x4){0.f, 0.f, 0.f, 0.f};

    const size_t kvbase = (size_t)bh * SS * 64;

    for (int kt = 0; kt < SS / KT2; ++kt) {
        {
            #pragma unroll
            for (int rr = 0; rr < 2; ++rr) {
                int slot = tid + 256 * rr;
                int key = slot >> 3, seg = slot & 7;
                size_t src = kvbase + (size_t)(kt * KT2 + key) * 64 + seg * 8;
                *(uint4*)(&KhL[key * LROW + seg * 8]) = *(const uint4*)(khws + src);
                *(uint4*)(&KlL[key * LROW + seg * 8]) = *(const uint4*)(klws + src);
            }
            int d2 = tid & 31;
            int kg = tid >> 5;
            const unsigned short* vp = vbf + kvbase + (size_t)(kt * KT2 + kg * 8) * 64 + d2 * 2;
            unsigned wv[8];
            #pragma unroll
            for (int j = 0; j < 8; ++j) wv[j] = *(const unsigned*)(vp + j * 64);
            uint4 E, O;
            E.x = (wv[0] & 0xffffu) | (wv[1] << 16);
            E.y = (wv[2] & 0xffffu) | (wv[3] << 16);
            E.z = (wv[4] & 0xffffu) | (wv[5] << 16);
            E.w = (wv[6] & 0xffffu) | (wv[7] << 16);
            O.x = (wv[0] >> 16) | (wv[1] & 0xffff0000u);
            O.y = (wv[2] >> 16) | (wv[3] & 0xffff0000u);
            O.z = (wv[4] >> 16) | (wv[5] & 0xffff0000u);
            O.w = (wv[6] >> 16) | (wv[7] & 0xffff0000u);
            *(uint4*)(&VtL[(2 * d2) * LROW + kg * 8]) = E;
            *(uint4*)(&VtL[(2 * d2 + 1) * LROW + kg * 8]) = O;
        }
        __syncthreads();

        f32x4 st[4];
        #pragma unroll
        for (int nf = 0; nf < 4; ++nf) {
            f32x4 acc = (f32x4){0.f, 0.f, 0.f, 0.f};
            #pragma unroll
            for (int kh = 0; kh < 2; ++kh) {
                int off = (nf * 16 + l15) * LROW + 32 * kh + 8 * g;
                short8 kah = *(const short8*)(&KhL[off]);
                short8 kal = *(const short8*)(&KlL[off]);
                acc = MFMA16(kah, qh[kh], acc, 0, 0, 0);
                acc = MFMA16(kah, ql[kh], acc, 0, 0, 0);
                acc = MFMA16(kal, qh[kh], acc, 0, 0, 0);
            }
            st[nf] = acc;
        }

        float tmax = -1e30f;
        #pragma unroll
        for (int nf = 0; nf < 4; ++nf)
            #pragma unroll
            for (int r = 0; r < 4; ++r) tmax = fmaxf(tmax, st[nf][r]);
        tmax = fmaxf(tmax, __shfl_xor(tmax, 16, 64));
        tmax = fmaxf(tmax, __shfl_xor(tmax, 32, 64));
        float newm = fmaxf(mrow, tmax);
        float alpha = __expf(mrow - newm);
        mrow = newm;
        float psum = 0.0f;
        #pragma unroll
        for (int nf = 0; nf < 4; ++nf) {
            unsigned short pb[4];
            #pragma unroll
            for (int r = 0; r < 4; ++r) {
                float p = __expf(st[nf][r] - newm);
                psum += p;
                pb[r] = f2bf(p);
            }
            uint2 pk;
            pk.x = (unsigned)pb[0] | ((unsigned)pb[1] << 16);
            pk.y = (unsigned)pb[2] | ((unsigned)pb[3] << 16);
            *(uint2*)(&PL[(w * 16 + l15) * LROW + nf * 16 + 4 * g]) = pk;
        }
        psum += __shfl_xor(psum, 16, 64);
        psum += __shfl_xor(psum, 32, 64);
        lrow = lrow * alpha + psum;

        #pragma unroll
        for (int r = 0; r < 4; ++r) {
            float ar = __shfl(alpha, 4 * g + r, 64);
            #pragma unroll
            for (int dt = 0; dt < 4; ++dt) oacc[dt][r] *= ar;
        }

        #pragma unroll
        for (int k2 = 0; k2 < 2; ++k2) {
            short8 pa = *(const short8*)(&PL[(w * 16 + l15) * LROW + k2 * 32 + 8 * g]);
            #pragma unroll
            for (int dt = 0; dt < 4; ++dt) {
                short8 vb = *(const short8*)(&VtL[(16 * dt + l15) * LROW + k2 * 32 + 8 * g]);
                oacc[dt] = MFMA16(pa, vb, oacc[dt], 0, 0, 0);
            }
        }
        __syncthreads();
    }

    float il = 1.0f / lrow;
    #pragma unroll
    for (int r = 0; r < 4; ++r) {
        float ilr = __shfl(il, 4 * g + r, 64);
        int row = qb0 + w * 16 + 4 * g + r;
        #pragma unroll
        for (int dt = 0; dt < 4; ++dt)
            ows[((size_t)bh * SS + row) * 64 + dt * 16 + l15] = oacc[dt][r] * ilr;
    }
}

// ---------------------------------------------------------------------------
// K3: LN2 + MLP via bf16 MFMA + residual.
// Block = 4 waves, 16 rows per iteration, ITERS row-groups per block.
// Wave w owns hidden chunk [64w, 64w+64): W1^T A-frags + W2 B-frags live in
// registers (loaded once). GEMM1 computed transposed (D[n][m]) so gelu output
// packs along hidden -> ds_write_b64 into Hs; read back as b128 A-frags for
// GEMM2 (same wave's chunk only -> no sync needed). Cross-wave K-reduction of
// GEMM2 partials through Rs (1 sync), fused residual + bias epilogue.
// ---------------------------------------------------------------------------
#define ITERS 4

__global__ __launch_bounds__(256) void k3_ln_mlp(
    const float* __restrict__ ows, const float* __restrict__ x,
    const float* __restrict__ g2, const float* __restrict__ b2v,
    const float* __restrict__ W1, const float* __restrict__ b1m,
    const float* __restrict__ W2, const float* __restrict__ b2o,
    float* __restrict__ out)
{
    __shared__ __align__(16) unsigned short Hs[16 * 264];   // [row][hidden], pad 264
    __shared__ __align__(16) float Rs[4 * 16 * 72];         // [wave][row][out], pad 72

    const int tid  = threadIdx.x;
    const int wv   = tid >> 6;
    const int lane = tid & 63;
    const int l15  = lane & 15;
    const int g    = lane >> 4;

    // ---- weight fragments, loaded once per block ----
    // w1f[t][kh]: A-frag of W1^T: element = W1[k][n], n = 64wv+16t+l15, k = 32kh+8g+j
    // w2f[t][kh]: B-frag of W2:   element = W2[k][n], n = 16t+l15, k = 64wv+32kh+8g+j
    short8 w1f[4][2], w2f[4][2];
    float  b1r[4][4];
    #pragma unroll
    for (int t = 0; t < 4; ++t) {
        #pragma unroll
        for (int kh = 0; kh < 2; ++kh) {
            #pragma unroll
            for (int j = 0; j < 8; ++j) {
                int k = kh * 32 + g * 8 + j;
                w1f[t][kh][j] = (short)f2bf(W1[k * 256 + wv * 64 + t * 16 + l15]);
                w2f[t][kh][j] = (short)f2bf(W2[(wv * 64 + k) * 64 + t * 16 + l15]);
            }
        }
        #pragma unroll
        for (int r = 0; r < 4; ++r)
            b1r[t][r] = b1m[wv * 64 + t * 16 + 4 * g + r];
    }

    for (int it = 0; it < ITERS; ++it) {
        const int r0 = (blockIdx.x * ITERS + it) * 16;

        // ---- LN2 for row (r0+l15); lane holds dims {32kh+8g+j} ----
        const float* orow = ows + (size_t)(r0 + l15) * 64;
        float hvv[16];
        #pragma unroll
        for (int kh = 0; kh < 2; ++kh) {
            float4 p0 = *(const float4*)(orow + kh * 32 + g * 8);
            float4 p1 = *(const float4*)(orow + kh * 32 + g * 8 + 4);
            hvv[kh*8+0]=p0.x; hvv[kh*8+1]=p0.y; hvv[kh*8+2]=p0.z; hvv[kh*8+3]=p0.w;
            hvv[kh*8+4]=p1.x; hvv[kh*8+5]=p1.y; hvv[kh*8+6]=p1.z; hvv[kh*8+7]=p1.w;
        }
        float s1 = 0.0f;
        #pragma unroll
        for (int i = 0; i < 16; ++i) s1 += hvv[i];
        s1 += __shfl_xor(s1, 16, 64);
        s1 += __shfl_xor(s1, 32, 64);
        float mean = s1 * (1.0f / 64.0f);
        float s2 = 0.0f;
        #pragma unroll
        for (int i = 0; i < 16; ++i) { float d = hvv[i] - mean; s2 += d * d; }
        s2 += __shfl_xor(s2, 16, 64);
        s2 += __shfl_xor(s2, 32, 64);
        float rstd = rsqrtf(s2 * (1.0f / 64.0f) + EPSV);

        short8 h2f[2];   // B-frags: B[k][m]: m = l15, k = 32kh+8g+j
        #pragma unroll
        for (int kh = 0; kh < 2; ++kh) {
            float4 ga = *(const float4*)(g2 + kh * 32 + g * 8);
            float4 gb = *(const float4*)(g2 + kh * 32 + g * 8 + 4);
            float4 ba = *(const float4*)(b2v + kh * 32 + g * 8);
            float4 bb = *(const float4*)(b2v + kh * 32 + g * 8 + 4);
            float gg[8] = {ga.x,ga.y,ga.z,ga.w,gb.x,gb.y,gb.z,gb.w};
            float bv[8] = {ba.x,ba.y,ba.z,ba.w,bb.x,bb.y,bb.z,bb.w};
            #pragma unroll
            for (int j = 0; j < 8; ++j)
                h2f[kh][j] = (short)f2bf((hvv[kh*8+j] - mean) * rstd * gg[j] + bv[j]);
        }

        // ---- GEMM1^T: D[n][m]; gelu; pack to Hs[m=l15][n] ----
        #pragma unroll
        for (int t = 0; t < 4; ++t) {
            f32x4 acc = (f32x4){0.f, 0.f, 0.f, 0.f};
            acc = MFMA16(w1f[t][0], h2f[0], acc, 0, 0, 0);
            acc = MFMA16(w1f[t][1], h2f[1], acc, 0, 0, 0);
            unsigned short pb[4];
            #pragma unroll
            for (int r = 0; r < 4; ++r) {
                float v = acc[r] + b1r[t][r];
                float ge = 0.5f * v * (1.0f + erff(v * 0.70710678118654752f));
                pb[r] = f2bf(ge);
            }
            uint2 pk;
            pk.x = (unsigned)pb[0] | ((unsigned)pb[1] << 16);
            pk.y = (unsigned)pb[2] | ((unsigned)pb[3] << 16);
            *(uint2*)(&Hs[l15 * 264 + wv * 64 + t * 16 + 4 * g]) = pk;
        }

        // ---- GEMM2 partial over this wave's hidden chunk ----
        short8 ha[2];
        ha[0] = *(const short8*)(&Hs[l15 * 264 + wv * 64 + g * 8]);
        ha[1] = *(const short8*)(&Hs[l15 * 264 + wv * 64 + 32 + g * 8]);
        #pragma unroll
        for (int t = 0; t < 4; ++t) {
            f32x4 a2 = (f32x4){0.f, 0.f, 0.f, 0.f};
            a2 = MFMA16(ha[0], w2f[t][0], a2, 0, 0, 0);
            a2 = MFMA16(ha[1], w2f[t][1], a2, 0, 0, 0);
            #pragma unroll
            for (int r = 0; r < 4; ++r)
                Rs[wv * 1152 + (4 * g + r) * 72 + t * 16 + l15] = a2[r];
        }
        __syncthreads();

        // ---- reduce 4 partials + bias + residual, store ----
        {
            int m = tid >> 4, d4 = tid & 15;
            const float* rp = Rs + m * 72 + d4 * 4;
            f32x4 v0 = *(const f32x4*)(rp);
            f32x4 v1 = *(const f32x4*)(rp + 1152);
            f32x4 v2 = *(const f32x4*)(rp + 2304);
            f32x4 v3 = *(const f32x4*)(rp + 3456);
            f32x4 sum = v0 + v1 + v2 + v3;
            int r = r0 + m;
            int b = r >> 14, h = (r >> 11) & 7, sq = r & 2047;
            size_t oidx = ((size_t)(b * 2048 + sq) * 8 + h) * 64 + d4 * 4;
            float4 xv = *(const float4*)(x + oidx);
            float4 bo = *(const float4*)(b2o + d4 * 4);
            float4 res = make_float4(sum[0] + xv.x + bo.x, sum[1] + xv.y + bo.y,
                                     sum[2] + xv.z + bo.z, sum[3] + xv.w + bo.w);
            *(float4*)(out + oidx) = res;
        }
        __syncthreads();
    }
}

// ---------------------------------------------------------------------------
extern "C" void kernel_launch(void* const* d_in, const int* in_sizes, int n_in,
                              void* d_out, int out_size, void* d_ws, size_t ws_size,
                              hipStream_t stream) {
    const float* x     = (const float*)d_in[0];
    const float* ln1_g = (const float*)d_in[1];
    const float* ln1_b = (const float*)d_in[2];
    const float* Wp    = (const float*)d_in[3];
    const float* bp    = (const float*)d_in[4];
    const float* ln2_g = (const float*)d_in[5];
    const float* ln2_b = (const float*)d_in[6];
    const float* W1    = (const float*)d_in[7];
    const float* b1    = (const float*)d_in[8];
    const float* W2    = (const float*)d_in[9];
    const float* b2    = (const float*)d_in[10];
    float* out = (float*)d_out;

    float* ws  = (float*)d_ws;
    float* qws = ws;
    float* ows = ws + 4194304;
    unsigned short* khws = (unsigned short*)(ws + 8388608);
    unsigned short* klws = khws + 4194304;
    unsigned short* vbf  = klws + 4194304;

    k1_ln_qkv<<<dim3(4096), dim3(256), 0, stream>>>(
        x, ln1_g, ln1_b, Wp, bp, qws, khws, klws, vbf);
    k2_attn<<<dim3(SS / 64, BB * HH), dim3(256), 0, stream>>>(
        qws, khws, klws, vbf, ows);
    k3_ln_mlp<<<dim3(BB * HH * SS / 16 / ITERS), dim3(256), 0, stream>>>(
        ows, x, ln2_g, ln2_b, W1, b1, W2, b2, out);
}

// Round 5
// 242.453 us; speedup vs baseline: 5.1281x; 1.1714x over previous
//
#include <hip/hip_runtime.h>
#include <hip/hip_bf16.h>
#include <math.h>

#define BB 4
#define SS 2048
#define HH 8
#define DD 64
#define EPSV 1e-5f

typedef __attribute__((ext_vector_type(8))) short short8;
typedef __attribute__((ext_vector_type(4))) float f32x4;
typedef unsigned short ushort_t;
#define MFMA16 __builtin_amdgcn_mfma_f32_16x16x32_bf16

__device__ inline unsigned short f2bf(float f) {
    unsigned u = __builtin_bit_cast(unsigned, f);
    unsigned r = (u + 0x7fffu + ((u >> 16) & 1u)) >> 16;
    return (unsigned short)r;
}
__device__ inline float bf2f(unsigned short h) {
    unsigned u = ((unsigned)h) << 16;
    return __builtin_bit_cast(float, u);
}
// packed f32x2 -> bf16x2 (v_cvt_pk_bf16_f32); memcpy instead of bit_cast
// because __hip_bfloat162 is not trivially copyable in this ROCm's headers.
__device__ inline unsigned pkbf(float a, float b) {
    __hip_bfloat162 h2 = __float22bfloat162_rn(make_float2(a, b));
    unsigned u;
    __builtin_memcpy(&u, &h2, 4);
    return u;
}

// ---------------------------------------------------------------------------
// K1: LN1 + QKV projection via bf16 MFMA, split-precision for Q and K.
// Grid: 512 blocks = 32 (b,h) x 16 s-chunks of 128. Block = 4 waves.
// Wave w holds B-frags (registers) for output col-tile w of Q, K, V.
// h (LN output) split hi/lo, shared across waves via LDS.
// Outputs: Q fp32 [bh][s][d]; K hi/lo bf16 [bh][s][d]; V^T bf16 [bh][d][s].
// ---------------------------------------------------------------------------
#define K1ITER 2

__global__ __launch_bounds__(256) void k1_ln_qkv(
    const float* __restrict__ x, const float* __restrict__ g1, const float* __restrict__ b1v,
    const float* __restrict__ Wp, const float* __restrict__ bp,
    float* __restrict__ qws, ushort_t* __restrict__ khws,
    ushort_t* __restrict__ klws, ushort_t* __restrict__ vtws)
{
    __shared__ __align__(16) ushort_t Hh[64 * 72];
    __shared__ __align__(16) ushort_t Hl[64 * 72];
    __shared__ __align__(16) ushort_t Vt[64 * 72];

    const int tid = threadIdx.x;
    const int wv  = tid >> 6;
    const int lane = tid & 63;
    const int l15 = lane & 15;
    const int g   = lane >> 4;
    const int bh  = blockIdx.x >> 4;     // b*8 + h
    const int sc  = blockIdx.x & 15;
    const int b   = bh >> 3, hh = bh & 7;

    // ---- B-frags: B[k][n], n = l15 (col within tile), k = 32kh+8g+j ----
    short8 bqh[2], bql[2], bkh[2], bkl[2], bvh[2];
    #pragma unroll
    for (int kh = 0; kh < 2; ++kh) {
        #pragma unroll
        for (int j = 0; j < 8; ++j) {
            int k = kh * 32 + g * 8 + j;
            float wq = Wp[k * 192 + wv * 16 + l15];
            float wk = Wp[k * 192 + 64 + wv * 16 + l15];
            float wvv = Wp[k * 192 + 128 + wv * 16 + l15];
            ushort_t qh_ = f2bf(wq); bqh[kh][j] = (short)qh_; bql[kh][j] = (short)f2bf(wq - bf2f(qh_));
            ushort_t kh_ = f2bf(wk); bkh[kh][j] = (short)kh_; bkl[kh][j] = (short)f2bf(wk - bf2f(kh_));
            bvh[kh][j] = (short)f2bf(wvv);
        }
    }
    const float biasq = bp[wv * 16 + l15];
    const float biask = bp[64 + wv * 16 + l15];
    const float biasv = bp[128 + wv * 16 + l15];

    for (int it = 0; it < K1ITER; ++it) {
        const int s0 = sc * 128 + it * 64;

        // ---- LN for row s0 + wv*16 + l15; lane holds dims 32kh+8g+j ----
        {
            const int srow = s0 + wv * 16 + l15;
            const float* xr = x + ((size_t)(b * 2048 + srow) * 8 + hh) * 64;
            float hvv[16];
            #pragma unroll
            for (int kh = 0; kh < 2; ++kh) {
                float4 p0 = *(const float4*)(xr + kh * 32 + g * 8);
                float4 p1 = *(const float4*)(xr + kh * 32 + g * 8 + 4);
                hvv[kh*8+0]=p0.x; hvv[kh*8+1]=p0.y; hvv[kh*8+2]=p0.z; hvv[kh*8+3]=p0.w;
                hvv[kh*8+4]=p1.x; hvv[kh*8+5]=p1.y; hvv[kh*8+6]=p1.z; hvv[kh*8+7]=p1.w;
            }
            float s1 = 0.0f;
            #pragma unroll
            for (int i = 0; i < 16; ++i) s1 += hvv[i];
            s1 += __shfl_xor(s1, 16, 64);
            s1 += __shfl_xor(s1, 32, 64);
            float mean = s1 * (1.0f / 64.0f);
            float s2 = 0.0f;
            #pragma unroll
            for (int i = 0; i < 16; ++i) { float d = hvv[i] - mean; s2 += d * d; }
            s2 += __shfl_xor(s2, 16, 64);
            s2 += __shfl_xor(s2, 32, 64);
            float rstd = rsqrtf(s2 * (1.0f / 64.0f) + EPSV);

            #pragma unroll
            for (int kh = 0; kh < 2; ++kh) {
                ushort_t hi[8]; unsigned lo2[4];
                float hf[8];
                #pragma unroll
                for (int j = 0; j < 8; ++j) {
                    int dI = kh * 32 + g * 8 + j;
                    hf[j] = (hvv[kh*8+j] - mean) * rstd * g1[dI] + b1v[dI];
                    hi[j] = f2bf(hf[j]);
                }
                uint4 HHv;
                HHv.x = (unsigned)hi[0] | ((unsigned)hi[1] << 16);
                HHv.y = (unsigned)hi[2] | ((unsigned)hi[3] << 16);
                HHv.z = (unsigned)hi[4] | ((unsigned)hi[5] << 16);
                HHv.w = (unsigned)hi[6] | ((unsigned)hi[7] << 16);
                #pragma unroll
                for (int j = 0; j < 4; ++j)
                    lo2[j] = pkbf(hf[2*j] - bf2f(hi[2*j]), hf[2*j+1] - bf2f(hi[2*j+1]));
                uint4 HLv; HLv.x = lo2[0]; HLv.y = lo2[1]; HLv.z = lo2[2]; HLv.w = lo2[3];
                int off = (wv * 16 + l15) * 72 + kh * 32 + g * 8;
                *(uint4*)(&Hh[off]) = HHv;
                *(uint4*)(&Hl[off]) = HLv;
            }
        }
        __syncthreads();

        // ---- GEMM over 4 m-tiles of 16 rows ----
        #pragma unroll
        for (int mt = 0; mt < 4; ++mt) {
            short8 ah[2], al[2];
            int abase = (mt * 16 + l15) * 72 + g * 8;
            ah[0] = *(const short8*)(&Hh[abase]);
            ah[1] = *(const short8*)(&Hh[abase + 32]);
            al[0] = *(const short8*)(&Hl[abase]);
            al[1] = *(const short8*)(&Hl[abase + 32]);

            f32x4 aq = (f32x4){0.f,0.f,0.f,0.f};
            f32x4 ak = (f32x4){0.f,0.f,0.f,0.f};
            f32x4 av = (f32x4){0.f,0.f,0.f,0.f};
            #pragma unroll
            for (int kh = 0; kh < 2; ++kh) {
                aq = MFMA16(ah[kh], bqh[kh], aq, 0, 0, 0);
                aq = MFMA16(al[kh], bqh[kh], aq, 0, 0, 0);
                aq = MFMA16(ah[kh], bql[kh], aq, 0, 0, 0);
                ak = MFMA16(ah[kh], bkh[kh], ak, 0, 0, 0);
                ak = MFMA16(al[kh], bkh[kh], ak, 0, 0, 0);
                ak = MFMA16(ah[kh], bkl[kh], ak, 0, 0, 0);
                av = MFMA16(ah[kh], bvh[kh], av, 0, 0, 0);
            }

            // epilogue: row = s0 + mt*16 + 4g + r; col = wv*16 + l15
            size_t base = ((size_t)bh * 2048 + s0 + mt * 16 + 4 * g) * 64 + wv * 16 + l15;
            #pragma unroll
            for (int r = 0; r < 4; ++r) {
                float q = aq[r] + biasq;
                qws[base + (size_t)r * 64] = q;
                float kf = ak[r] + biask;
                ushort_t k16 = f2bf(kf);
                khws[base + (size_t)r * 64] = k16;
                klws[base + (size_t)r * 64] = f2bf(kf - bf2f(k16));
            }
            uint2 vvp;
            vvp.x = pkbf(av[0] + biasv, av[1] + biasv);
            vvp.y = pkbf(av[2] + biasv, av[3] + biasv);
            *(uint2*)(&Vt[(wv * 16 + l15) * 72 + mt * 16 + 4 * g]) = vvp;
        }
        __syncthreads();

        // ---- cooperative V^T store: rows = d, 128 B per row ----
        #pragma unroll
        for (int p = 0; p < 2; ++p) {
            int slot = tid + 256 * p;
            int dd = slot >> 3, cc = slot & 7;
            *(uint4*)(vtws + ((size_t)bh * 64 + dd) * 2048 + s0 + cc * 8) =
                *(const uint4*)(&Vt[dd * 72 + cc * 8]);
        }
    }
}

// ---------------------------------------------------------------------------
// K2: flash attention, bf16 MFMA, split-precision QK^T. V^T pre-transposed.
// ---------------------------------------------------------------------------
#define KT2 64
#define LROW 72

__global__ __launch_bounds__(256) void k2_attn(
    const float* __restrict__ qws, const ushort_t* __restrict__ khws,
    const ushort_t* __restrict__ klws, const ushort_t* __restrict__ vtws,
    float* __restrict__ ows)
{
    __shared__ __align__(16) ushort_t KhL[64 * LROW];
    __shared__ __align__(16) ushort_t KlL[64 * LROW];
    __shared__ __align__(16) ushort_t VtL[64 * LROW];   // [dim][key]
    __shared__ __align__(16) ushort_t PL[4 * 16 * LROW];

    const int tid  = threadIdx.x;
    const int w    = tid >> 6;
    const int lane = tid & 63;
    const int l15  = lane & 15;
    const int g    = lane >> 4;
    const int bh   = blockIdx.y;
    const int qb0  = blockIdx.x * 64;

    short8 qh[2], ql[2];
    {
        const float* qp = qws + ((size_t)bh * SS + qb0 + w * 16 + l15) * 64;
        #pragma unroll
        for (int kh = 0; kh < 2; ++kh) {
            const float* p = qp + 32 * kh + 8 * g;
            #pragma unroll
            for (int j = 0; j < 8; ++j) {
                float f = p[j];
                ushort_t hi = f2bf(f);
                qh[kh][j] = (short)hi;
                ql[kh][j] = (short)f2bf(f - bf2f(hi));
            }
        }
    }

    float mrow = -1e30f, lrow = 0.0f;
    f32x4 oacc[4];
    #pragma unroll
    for (int dt = 0; dt < 4; ++dt) oacc[dt] = (f32x4){0.f, 0.f, 0.f, 0.f};

    const size_t kvbase = (size_t)bh * SS * 64;
    const size_t vtbase = (size_t)bh * 64 * 2048;

    for (int kt = 0; kt < SS / KT2; ++kt) {
        // ---- stage K hi/lo (row=key) and V^T (row=dim) — plain copies ----
        #pragma unroll
        for (int rr = 0; rr < 2; ++rr) {
            int slot = tid + 256 * rr;              // 0..511
            int row = slot >> 3, seg = slot & 7;
            size_t ksrc = kvbase + (size_t)(kt * KT2 + row) * 64 + seg * 8;
            *(uint4*)(&KhL[row * LROW + seg * 8]) = *(const uint4*)(khws + ksrc);
            *(uint4*)(&KlL[row * LROW + seg * 8]) = *(const uint4*)(klws + ksrc);
            size_t vsrc = vtbase + (size_t)row * 2048 + kt * KT2 + seg * 8;
            *(uint4*)(&VtL[row * LROW + seg * 8]) = *(const uint4*)(vtws + vsrc);
        }
        __syncthreads();

        // ---- S^T = K·Q^T : 4 key-subtiles of 16, split-precision ----
        f32x4 st[4];
        #pragma unroll
        for (int nf = 0; nf < 4; ++nf) {
            f32x4 acc = (f32x4){0.f, 0.f, 0.f, 0.f};
            #pragma unroll
            for (int kh = 0; kh < 2; ++kh) {
                int off = (nf * 16 + l15) * LROW + 32 * kh + 8 * g;
                short8 kah = *(const short8*)(&KhL[off]);
                short8 kal = *(const short8*)(&KlL[off]);
                acc = MFMA16(kah, qh[kh], acc, 0, 0, 0);
                acc = MFMA16(kah, ql[kh], acc, 0, 0, 0);
                acc = MFMA16(kal, qh[kh], acc, 0, 0, 0);
            }
            st[nf] = acc;   // key = kt*64 + nf*16 + 4g + r ; q = qb0 + w*16 + l15
        }

        // ---- online softmax (state keyed by q = l15) ----
        float tmax = -1e30f;
        #pragma unroll
        for (int nf = 0; nf < 4; ++nf)
            #pragma unroll
            for (int r = 0; r < 4; ++r) tmax = fmaxf(tmax, st[nf][r]);
        tmax = fmaxf(tmax, __shfl_xor(tmax, 16, 64));
        tmax = fmaxf(tmax, __shfl_xor(tmax, 32, 64));
        float newm = fmaxf(mrow, tmax);
        float alpha = __expf(mrow - newm);
        mrow = newm;
        float psum = 0.0f;
        #pragma unroll
        for (int nf = 0; nf < 4; ++nf) {
            float p0 = __expf(st[nf][0] - newm);
            float p1 = __expf(st[nf][1] - newm);
            float p2 = __expf(st[nf][2] - newm);
            float p3 = __expf(st[nf][3] - newm);
            psum += (p0 + p1) + (p2 + p3);
            uint2 pk;
            pk.x = pkbf(p0, p1);
            pk.y = pkbf(p2, p3);
            *(uint2*)(&PL[(w * 16 + l15) * LROW + nf * 16 + 4 * g]) = pk;
        }
        psum += __shfl_xor(psum, 16, 64);
        psum += __shfl_xor(psum, 32, 64);
        lrow = lrow * alpha + psum;

        #pragma unroll
        for (int r = 0; r < 4; ++r) {
            float ar = __shfl(alpha, 4 * g + r, 64);
            #pragma unroll
            for (int dt = 0; dt < 4; ++dt) oacc[dt][r] *= ar;
        }

        // ---- O += P·V ----
        #pragma unroll
        for (int k2 = 0; k2 < 2; ++k2) {
            short8 pa = *(const short8*)(&PL[(w * 16 + l15) * LROW + k2 * 32 + 8 * g]);
            #pragma unroll
            for (int dt = 0; dt < 4; ++dt) {
                short8 vb = *(const short8*)(&VtL[(16 * dt + l15) * LROW + k2 * 32 + 8 * g]);
                oacc[dt] = MFMA16(pa, vb, oacc[dt], 0, 0, 0);
            }
        }
        __syncthreads();
    }

    float il = 1.0f / lrow;
    #pragma unroll
    for (int r = 0; r < 4; ++r) {
        float ilr = __shfl(il, 4 * g + r, 64);
        int row = qb0 + w * 16 + 4 * g + r;
        #pragma unroll
        for (int dt = 0; dt < 4; ++dt)
            ows[((size_t)bh * SS + row) * 64 + dt * 16 + l15] = oacc[dt][r] * ilr;
    }
}

// ---------------------------------------------------------------------------
// K3: LN2 + MLP via bf16 MFMA + residual. (unchanged structure)
// ---------------------------------------------------------------------------
#define ITERS 4

__global__ __launch_bounds__(256) void k3_ln_mlp(
    const float* __restrict__ ows, const float* __restrict__ x,
    const float* __restrict__ g2, const float* __restrict__ b2v,
    const float* __restrict__ W1, const float* __restrict__ b1m,
    const float* __restrict__ W2, const float* __restrict__ b2o,
    float* __restrict__ out)
{
    __shared__ __align__(16) ushort_t Hs[16 * 264];
    __shared__ __align__(16) float Rs[4 * 16 * 72];

    const int tid  = threadIdx.x;
    const int wv   = tid >> 6;
    const int lane = tid & 63;
    const int l15  = lane & 15;
    const int g    = lane >> 4;

    short8 w1f[4][2], w2f[4][2];
    float  b1r[4][4];
    #pragma unroll
    for (int t = 0; t < 4; ++t) {
        #pragma unroll
        for (int kh = 0; kh < 2; ++kh) {
            #pragma unroll
            for (int j = 0; j < 8; ++j) {
                int k = kh * 32 + g * 8 + j;
                w1f[t][kh][j] = (short)f2bf(W1[k * 256 + wv * 64 + t * 16 + l15]);
                w2f[t][kh][j] = (short)f2bf(W2[(wv * 64 + k) * 64 + t * 16 + l15]);
            }
        }
        #pragma unroll
        for (int r = 0; r < 4; ++r)
            b1r[t][r] = b1m[wv * 64 + t * 16 + 4 * g + r];
    }

    for (int it = 0; it < ITERS; ++it) {
        const int r0 = (blockIdx.x * ITERS + it) * 16;

        const float* orow = ows + (size_t)(r0 + l15) * 64;
        float hvv[16];
        #pragma unroll
        for (int kh = 0; kh < 2; ++kh) {
            float4 p0 = *(const float4*)(orow + kh * 32 + g * 8);
            float4 p1 = *(const float4*)(orow + kh * 32 + g * 8 + 4);
            hvv[kh*8+0]=p0.x; hvv[kh*8+1]=p0.y; hvv[kh*8+2]=p0.z; hvv[kh*8+3]=p0.w;
            hvv[kh*8+4]=p1.x; hvv[kh*8+5]=p1.y; hvv[kh*8+6]=p1.z; hvv[kh*8+7]=p1.w;
        }
        float s1 = 0.0f;
        #pragma unroll
        for (int i = 0; i < 16; ++i) s1 += hvv[i];
        s1 += __shfl_xor(s1, 16, 64);
        s1 += __shfl_xor(s1, 32, 64);
        float mean = s1 * (1.0f / 64.0f);
        float s2 = 0.0f;
        #pragma unroll
        for (int i = 0; i < 16; ++i) { float d = hvv[i] - mean; s2 += d * d; }
        s2 += __shfl_xor(s2, 16, 64);
        s2 += __shfl_xor(s2, 32, 64);
        float rstd = rsqrtf(s2 * (1.0f / 64.0f) + EPSV);

        short8 h2f[2];
        #pragma unroll
        for (int kh = 0; kh < 2; ++kh) {
            float4 ga = *(const float4*)(g2 + kh * 32 + g * 8);
            float4 gb = *(const float4*)(g2 + kh * 32 + g * 8 + 4);
            float4 ba = *(const float4*)(b2v + kh * 32 + g * 8);
            float4 bb = *(const float4*)(b2v + kh * 32 + g * 8 + 4);
            float gg[8] = {ga.x,ga.y,ga.z,ga.w,gb.x,gb.y,gb.z,gb.w};
            float bv[8] = {ba.x,ba.y,ba.z,ba.w,bb.x,bb.y,bb.z,bb.w};
            #pragma unroll
            for (int j = 0; j < 8; ++j)
                h2f[kh][j] = (short)f2bf((hvv[kh*8+j] - mean) * rstd * gg[j] + bv[j]);
        }

        #pragma unroll
        for (int t = 0; t < 4; ++t) {
            f32x4 acc = (f32x4){0.f, 0.f, 0.f, 0.f};
            acc = MFMA16(w1f[t][0], h2f[0], acc, 0, 0, 0);
            acc = MFMA16(w1f[t][1], h2f[1], acc, 0, 0, 0);
            float ge[4];
            #pragma unroll
            for (int r = 0; r < 4; ++r) {
                float v = acc[r] + b1r[t][r];
                ge[r] = 0.5f * v * (1.0f + erff(v * 0.70710678118654752f));
            }
            uint2 pk;
            pk.x = pkbf(ge[0], ge[1]);
            pk.y = pkbf(ge[2], ge[3]);
            *(uint2*)(&Hs[l15 * 264 + wv * 64 + t * 16 + 4 * g]) = pk;
        }

        short8 ha[2];
        ha[0] = *(const short8*)(&Hs[l15 * 264 + wv * 64 + g * 8]);
        ha[1] = *(const short8*)(&Hs[l15 * 264 + wv * 64 + 32 + g * 8]);
        #pragma unroll
        for (int t = 0; t < 4; ++t) {
            f32x4 a2 = (f32x4){0.f, 0.f, 0.f, 0.f};
            a2 = MFMA16(ha[0], w2f[t][0], a2, 0, 0, 0);
            a2 = MFMA16(ha[1], w2f[t][1], a2, 0, 0, 0);
            #pragma unroll
            for (int r = 0; r < 4; ++r)
                Rs[wv * 1152 + (4 * g + r) * 72 + t * 16 + l15] = a2[r];
        }
        __syncthreads();

        {
            int m = tid >> 4, d4 = tid & 15;
            const float* rp = Rs + m * 72 + d4 * 4;
            f32x4 v0 = *(const f32x4*)(rp);
            f32x4 v1 = *(const f32x4*)(rp + 1152);
            f32x4 v2 = *(const f32x4*)(rp + 2304);
            f32x4 v3 = *(const f32x4*)(rp + 3456);
            f32x4 sum = v0 + v1 + v2 + v3;
            int r = r0 + m;
            int bq = r >> 14, hq = (r >> 11) & 7, sq = r & 2047;
            size_t oidx = ((size_t)(bq * 2048 + sq) * 8 + hq) * 64 + d4 * 4;
            float4 xv = *(const float4*)(x + oidx);
            float4 bo = *(const float4*)(b2o + d4 * 4);
            float4 res = make_float4(sum[0] + xv.x + bo.x, sum[1] + xv.y + bo.y,
                                     sum[2] + xv.z + bo.z, sum[3] + xv.w + bo.w);
            *(float4*)(out + oidx) = res;
        }
        __syncthreads();
    }
}

// ---------------------------------------------------------------------------
extern "C" void kernel_launch(void* const* d_in, const int* in_sizes, int n_in,
                              void* d_out, int out_size, void* d_ws, size_t ws_size,
                              hipStream_t stream) {
    const float* x     = (const float*)d_in[0];
    const float* ln1_g = (const float*)d_in[1];
    const float* ln1_b = (const float*)d_in[2];
    const float* Wp    = (const float*)d_in[3];
    const float* bp    = (const float*)d_in[4];
    const float* ln2_g = (const float*)d_in[5];
    const float* ln2_b = (const float*)d_in[6];
    const float* W1    = (const float*)d_in[7];
    const float* b1    = (const float*)d_in[8];
    const float* W2    = (const float*)d_in[9];
    const float* b2    = (const float*)d_in[10];
    float* out = (float*)d_out;

    // workspace: qws f32 | ows f32 | khws bf16 | klws bf16 | vtws bf16 (58.7 MB)
    float* ws  = (float*)d_ws;
    float* qws = ws;
    float* ows = ws + 4194304;
    ushort_t* khws = (ushort_t*)(ws + 8388608);
    ushort_t* klws = khws + 4194304;
    ushort_t* vtws = klws + 4194304;

    k1_ln_qkv<<<dim3(512), dim3(256), 0, stream>>>(
        x, ln1_g, ln1_b, Wp, bp, qws, khws, klws, vtws);
    k2_attn<<<dim3(SS / 64, BB * HH), dim3(256), 0, stream>>>(
        qws, khws, klws, vtws, ows);
    k3_ln_mlp<<<dim3(BB * HH * SS / 16 / ITERS), dim3(256), 0, stream>>>(
        ows, x, ln2_g, ln2_b, W1, b1, W2, b2, out);
}